// Round 19
// baseline (392.198 us; speedup 1.0000x reference)
//
#include <hip/hip_runtime.h>
#include <math.h>

typedef unsigned short u16;
typedef short s16x8 __attribute__((ext_vector_type(8)));
typedef float f32x4 __attribute__((ext_vector_type(4)));
typedef u16 u16x4 __attribute__((ext_vector_type(4)));

#define D 1024
#define MM 2048   // B*S
#define HH 512
#define VV 32000

static __device__ __forceinline__ u16 f2bf(float f) {
    union { float f; unsigned int i; } c; c.f = f;
    unsigned int x = c.i;
    return (u16)((x + 0x7fffu + ((x >> 16) & 1u)) >> 16);  // RNE
}
static __device__ __forceinline__ float sigm(float x) { return 1.0f / (1.0f + expf(-x)); }

static __device__ __forceinline__ void load_lds16(const u16* g, u16* l) {
    __builtin_amdgcn_global_load_lds(
        (const __attribute__((address_space(1))) unsigned int*)g,
        (__attribute__((address_space(3))) unsigned int*)l, 16, 0, 0);
}

// ---------------- f32 -> bf16 convert, NT input ----------------
__global__ __launch_bounds__(256) void cvt_kernel(const float* __restrict__ in,
                                                  u16* __restrict__ out, const int n4)
{
    for (int i = blockIdx.x * 256 + threadIdx.x; i < n4; i += gridDim.x * 256) {
        f32x4 v = __builtin_nontemporal_load((const f32x4*)in + i);
        u16x4 o;
#pragma unroll
        for (int j = 0; j < 4; j++) o[j] = f2bf(v[j]);
        ((u16x4*)out)[i] = o;
    }
}

// ---------------- prep body (Wcat + W2eff for one layer), callable ----------------
static __device__ __forceinline__ void prep_body(int bid,
    const float* __restrict__ baseW, const float* __restrict__ W1,
    const float* __restrict__ W2l, const float* __restrict__ gatel,
    const float* __restrict__ tors, const float* __restrict__ pW,
    const float* __restrict__ pb, u16* __restrict__ Wcat, u16* __restrict__ W2eff)
{
    if (bid < 1024) {
        const int B4 = 1024 * 1024 / 4;
#pragma unroll
        for (int it = 0; it < 3; ++it) {
            const int i = (it * 1024 + bid) * 256 + threadIdx.x;
            f32x4 v = (i < B4) ? __builtin_nontemporal_load((const f32x4*)baseW + i)
                               : __builtin_nontemporal_load((const f32x4*)W1 + (i - B4));
            u16x4 o;
#pragma unroll
            for (int j = 0; j < 4; j++) o[j] = f2bf(v[j]);
            ((u16x4*)Wcat)[i] = o;
        }
    } else {
        bid -= 1024;        // 2048 blocks for W2eff
        const float NS = 1.0f / (1.0f + expf(-0.70710678118654752f));
        float e[4], sum = 0.0f;
#pragma unroll
        for (int k = 0; k < 4; k++) {
            float a = pb[k] + 0.5f * (pW[k*4] + pW[k*4+1] + pW[k*4+2] + pW[k*4+3]);
            e[k] = 0.6f * sigm(a) + 0.4f * NS;
            sum += e[k];
        }
        const int n = bid >> 1;
        const int half = bid & 1;
        const int kh = half * 1024 + threadIdx.x * 4;
        const int k = kh >> 9;
        const int hh = kh & 511;
        const float f = sigm(gatel[k * D + n] + tors[n]) * (e[k] / sum);
        f32x4 w = __builtin_nontemporal_load((const f32x4*)&W2l[((long)k * D + n) * HH + hh]);
        u16x4 o;
#pragma unroll
        for (int i = 0; i < 4; i++) o[i] = f2bf(w[i] * f);
        *(u16x4*)&W2eff[(long)n * 2048 + kh] = o;
    }
}

// ---------------- per-layer prep (fallback path) ----------------
__global__ __launch_bounds__(256) void prep_kernel(
    const float* __restrict__ baseW, const float* __restrict__ W1,
    const float* __restrict__ W2l, const float* __restrict__ gatel,
    const float* __restrict__ tors, const float* __restrict__ pW,
    const float* __restrict__ pb, u16* __restrict__ Wcat, u16* __restrict__ W2eff)
{
    prep_body(blockIdx.x, baseW, W1, W2l, gatel, tors, pW, pb, Wcat, W2eff);
}

// ---------------- mega-prep: ALL weight prep (both layers + lmW cvt) in one launch ----------------
__global__ __launch_bounds__(256) void mega_prep_kernel(
    const float* __restrict__ baseW, const float* __restrict__ W1,
    const float* __restrict__ W2, const float* __restrict__ gate,
    const float* __restrict__ tors, const float* __restrict__ propW,
    const float* __restrict__ propb, const float* __restrict__ lmW,
    u16* __restrict__ Wcat0, u16* __restrict__ W2eff0,
    u16* __restrict__ Wcat1, u16* __restrict__ W2eff1, u16* __restrict__ lmWbf)
{
    const int bid = blockIdx.x;   // 8192 blocks
    if (bid < 6144) {
        const int l = bid < 3072 ? 0 : 1;
        prep_body(bid - l * 3072,
                  baseW + (long)l * D * D, W1 + (long)l * 4 * HH * D,
                  W2 + (long)l * 4 * D * HH, gate + (long)l * 4 * D, tors,
                  propW + l * 16, propb + l * 4,
                  l ? Wcat1 : Wcat0, l ? W2eff1 : W2eff0);
    } else {
        const int n4 = VV * D / 4;
        for (int i = (bid - 6144) * 256 + threadIdx.x; i < n4; i += 2048 * 256) {
            f32x4 v = __builtin_nontemporal_load((const f32x4*)lmW + i);
            u16x4 o;
#pragma unroll
            for (int j = 0; j < 4; j++) o[j] = f2bf(v[j]);
            ((u16x4*)lmWbf)[i] = o;
        }
    }
}

// ---------------- embed + LN1[0] ----------------
__global__ __launch_bounds__(256) void embed_ln_kernel(const int* __restrict__ ids,
    const float* __restrict__ emb, const float* __restrict__ pos,
    const float* __restrict__ g, const float* __restrict__ b,
    float* __restrict__ h, u16* __restrict__ hn)
{
    const int m = blockIdx.x;
    const int s = m & 1023;
    const long id = ids[m];
    const int d = threadIdx.x * 4;
    f32x4 ev = *(const f32x4*)&emb[id * D + d];
    f32x4 pv = *(const f32x4*)&pos[(long)s * D + d];
    f32x4 x;
#pragma unroll
    for (int i = 0; i < 4; i++) x[i] = ev[i] + pv[i];
    *(f32x4*)&h[(long)m * D + d] = x;

    float sm = x[0] + x[1] + x[2] + x[3];
    float ss = x[0]*x[0] + x[1]*x[1] + x[2]*x[2] + x[3]*x[3];
#pragma unroll
    for (int off = 32; off; off >>= 1) { sm += __shfl_xor(sm, off); ss += __shfl_xor(ss, off); }
    __shared__ float red[8];
    const int wid = threadIdx.x >> 6;
    if ((threadIdx.x & 63) == 0) { red[wid] = sm; red[4 + wid] = ss; }
    __syncthreads();
    sm = red[0] + red[1] + red[2] + red[3];
    ss = red[4] + red[5] + red[6] + red[7];
    const float mu = sm * (1.0f / D);
    const float rstd = rsqrtf(ss * (1.0f / D) - mu * mu + 1e-5f);
    f32x4 gv = *(const f32x4*)&g[d];
    f32x4 bv = *(const f32x4*)&b[d];
    u16x4 o;
#pragma unroll
    for (int i = 0; i < 4; i++) o[i] = f2bf((x[i] - mu) * rstd * gv[i] + bv[i]);
    *(u16x4*)&hn[(long)m * D + d] = o;
}

// ------- fused: h = LN2(h + 0.3*(C + P0+P1+P2+P3)); hn = bf16(LNnext(h)) -------
__global__ __launch_bounds__(256) void resln2_kernel(float* __restrict__ h,
    const float* __restrict__ c, const float* __restrict__ P,
    const float* __restrict__ g2, const float* __restrict__ b2,
    const float* __restrict__ gn, const float* __restrict__ bn_, u16* __restrict__ hn)
{
    const int row = blockIdx.x;
    const int d = threadIdx.x * 4;
    const long off = (long)row * D + d;
    f32x4 x = *(const f32x4*)&h[off];
    f32x4 cv = *(const f32x4*)&c[off];
    f32x4 p0 = *(const f32x4*)&P[off];
    f32x4 p1 = *(const f32x4*)&P[off + (1l << 21)];
    f32x4 p2 = *(const f32x4*)&P[off + (2l << 21)];
    f32x4 p3 = *(const f32x4*)&P[off + (3l << 21)];
#pragma unroll
    for (int i = 0; i < 4; i++) x[i] += 0.3f * (cv[i] + ((p0[i] + p1[i]) + (p2[i] + p3[i])));
    float sm = x[0] + x[1] + x[2] + x[3];
    float ss = x[0]*x[0] + x[1]*x[1] + x[2]*x[2] + x[3]*x[3];
#pragma unroll
    for (int off2 = 32; off2; off2 >>= 1) { sm += __shfl_xor(sm, off2); ss += __shfl_xor(ss, off2); }
    __shared__ float red[8];
    const int wid = threadIdx.x >> 6;
    if ((threadIdx.x & 63) == 0) { red[wid] = sm; red[4 + wid] = ss; }
    __syncthreads();
    sm = red[0] + red[1] + red[2] + red[3];
    ss = red[4] + red[5] + red[6] + red[7];
    float mu = sm * (1.0f / D);
    float rstd = rsqrtf(ss * (1.0f / D) - mu * mu + 1e-5f);
    f32x4 g2v = *(const f32x4*)&g2[d];
    f32x4 b2v = *(const f32x4*)&b2[d];
    f32x4 y;
#pragma unroll
    for (int i = 0; i < 4; i++) y[i] = (x[i] - mu) * rstd * g2v[i] + b2v[i];
    *(f32x4*)&h[off] = y;

    sm = y[0] + y[1] + y[2] + y[3];
    ss = y[0]*y[0] + y[1]*y[1] + y[2]*y[2] + y[3]*y[3];
#pragma unroll
    for (int off2 = 32; off2; off2 >>= 1) { sm += __shfl_xor(sm, off2); ss += __shfl_xor(ss, off2); }
    __syncthreads();
    if ((threadIdx.x & 63) == 0) { red[wid] = sm; red[4 + wid] = ss; }
    __syncthreads();
    sm = red[0] + red[1] + red[2] + red[3];
    ss = red[4] + red[5] + red[6] + red[7];
    mu = sm * (1.0f / D);
    rstd = rsqrtf(ss * (1.0f / D) - mu * mu + 1e-5f);
    f32x4 gnv = *(const f32x4*)&gn[d];
    f32x4 bnv = *(const f32x4*)&bn_[d];
    u16x4 o;
#pragma unroll
    for (int i = 0; i < 4; i++) o[i] = f2bf((y[i] - mu) * rstd * gnv[i] + bnv[i]);
    *(u16x4*)&hn[off] = o;
}

// ---------------- layer GEMM: 128x128, 4 waves, BK=32, fragment-linear LDS ----------------
// EPI 3: mixed -> n<1024: f32 C; n>=1024: gelu->bf16 t. EPI 5: f32 store to partial[z].
template<int EPI>
__global__ __launch_bounds__(256) void gemm_t(
    const u16* __restrict__ A, const u16* __restrict__ W,
    float* __restrict__ Cf, u16* __restrict__ Cb,
    const int Kloop, const int ldk, const long ldc)
{
    if (EPI == 5) { A += blockIdx.z * 512; W += blockIdx.z * 512; Cf += (long)blockIdx.z << 21; }

    const int gx = gridDim.x;
    const int nwg = gx * gridDim.y;
    int lin = blockIdx.y * gx + blockIdx.x;
    lin = (lin & 7) * (nwg >> 3) + (lin >> 3);
    const int bm = (lin % gx) * 128;
    const int bn = (lin / gx) * 128;

    __shared__ __align__(16) u16 AB[8192];

    const int tid = threadIdx.x, lane = tid & 63, w = tid >> 6;
    const int wm = w >> 1, wn = w & 1;
    const int l15 = lane & 15, lk8 = (lane >> 4) * 8;

    const u16* src[4];
    u16* dst[4];
#pragma unroll
    for (int ci = 0; ci < 4; ++ci) {
        const int c = w + ci * 4;
        src[ci] = (c < 8 ? A + (long)(bm + c * 16 + l15) * ldk
                         : W + (long)(bn + (c - 8) * 16 + l15) * ldk) + lk8;
        dst[ci] = AB + c * 512;
    }

    f32x4 acc[4][4];
#pragma unroll
    for (int i = 0; i < 4; ++i)
#pragma unroll
        for (int j = 0; j < 4; ++j) acc[i][j] = f32x4{0.f, 0.f, 0.f, 0.f};

    for (int k0 = 0; k0 < Kloop; k0 += 32) {
        __syncthreads();
#pragma unroll
        for (int ci = 0; ci < 4; ++ci) load_lds16(src[ci] + k0, dst[ci]);
        __syncthreads();
        s16x8 a[4], b[4];
#pragma unroll
        for (int i = 0; i < 4; ++i) a[i] = *(const s16x8*)(AB + (wm * 4 + i) * 512 + lane * 8);
#pragma unroll
        for (int j = 0; j < 4; ++j) b[j] = *(const s16x8*)(AB + (8 + wn * 4 + j) * 512 + lane * 8);
#pragma unroll
        for (int i = 0; i < 4; ++i)
#pragma unroll
            for (int j = 0; j < 4; ++j)
                acc[i][j] = __builtin_amdgcn_mfma_f32_16x16x32_bf16(a[i], b[j], acc[i][j], 0, 0, 0);
    }

    const int r0 = (lane >> 4) * 4;
#pragma unroll
    for (int i = 0; i < 4; ++i) {
#pragma unroll
        for (int j = 0; j < 4; ++j) {
            const int n = bn + wn * 64 + j * 16 + l15;
#pragma unroll
            for (int rr = 0; rr < 4; ++rr) {
                const int m = bm + wm * 64 + i * 16 + r0 + rr;
                const float v = acc[i][j][rr];
                if (EPI == 3) {
                    if (n < 1024) {
                        Cf[(long)m * 1024 + n] = v;
                    } else {
                        const float gel = 0.5f * v * (1.0f + erff(v * 0.70710678118654752f));
                        Cb[(long)m * 2048 + (n - 1024)] = f2bf(gel);
                    }
                } else {  // EPI == 5: plain f32 partial store
                    Cf[(long)m * ldc + n] = v;
                }
            }
        }
    }
}

// ================= lm_head: 256x256, BK=64, frag-prefetch (r8 engine, plain stores) ========
#define AU16  16384
#define HALFU 8192
#define BB0   32768

__global__ __launch_bounds__(512, 2) void gemm256_kernel(
    const u16* __restrict__ Ag, const u16* __restrict__ Wg, float* __restrict__ C)
{
    __shared__ __align__(16) u16 lds[65536];

    const int nwg = gridDim.x * gridDim.y;
    int lin = blockIdx.y * gridDim.x + blockIdx.x;
    lin = (lin & 7) * (nwg >> 3) + (lin >> 3);
    const int bm = (lin & 7) * 256;
    const int bn = (lin >> 3) * 256;

    const int tid = threadIdx.x;
    const int lane = tid & 63;
    const int w = tid >> 6;
    const int wm = w >> 2;
    const int wn = w & 3;

    const u16* aSrc = Ag + (long)(bm + w * 16 + (lane & 15)) * 1024 + ((lane >> 4) * 8);
    const u16* bSrc = Wg + (long)(bn + w * 16 + (lane & 15)) * 1024 + ((lane >> 4) * 8);
    u16* aDst = lds + w * 1024;
    u16* bDst = lds + BB0 + w * 1024;

    auto stageA = [&](int kt, int b, int kk) {
        const long co = (long)kt * 64 + kk * 32;
        load_lds16(aSrc + co,               aDst + b * AU16 + kk * 512);
        load_lds16(aSrc + co + 128 * 1024L, aDst + b * AU16 + HALFU + kk * 512);
    };
    auto stageB = [&](int kt, int b, int kk) {
        const long co = (long)kt * 64 + kk * 32;
        load_lds16(bSrc + co,               bDst + b * AU16 + kk * 512);
        load_lds16(bSrc + co + 128 * 1024L, bDst + b * AU16 + HALFU + kk * 512);
    };

    const u16* aRd = lds + wm * HALFU + lane * 8;
    const u16* bRd = lds + BB0 + (wn >> 1) * HALFU + (wn & 1) * 4096 + lane * 8;

    f32x4 acc[8][4];
#pragma unroll
    for (int i = 0; i < 8; ++i)
#pragma unroll
        for (int j = 0; j < 4; ++j) acc[i][j] = f32x4{0.f, 0.f, 0.f, 0.f};

    s16x8 F0[12], F1[12];

    stageA(0, 0, 0); stageB(0, 0, 0);
    stageA(0, 0, 1); stageB(0, 0, 1);
    stageA(1, 1, 0); stageB(1, 1, 0);
    asm volatile("s_waitcnt vmcnt(4)" ::: "memory");
    __builtin_amdgcn_s_barrier();
    __builtin_amdgcn_sched_barrier(0);

#pragma unroll
    for (int i = 0; i < 8; ++i) F0[i] = *(const s16x8*)(aRd + i * 1024);
#pragma unroll
    for (int j = 0; j < 4; ++j) F0[8 + j] = *(const s16x8*)(bRd + j * 1024);

    auto phase = [&](int p, s16x8 (&fu)[12], s16x8 (&fl)[12]) {
        const int pr = p + 1;
        const int Tr = (pr >> 1) & 15, kkr = pr & 1, br = Tr & 1;
        const u16* aR = aRd + br * AU16 + kkr * 512;
        const u16* bR = bRd + br * AU16 + kkr * 512;
#pragma unroll
        for (int i = 0; i < 8; ++i) fl[i] = *(const s16x8*)(aR + i * 1024);
#pragma unroll
        for (int j = 0; j < 4; ++j) fl[8 + j] = *(const s16x8*)(bR + j * 1024);
        const int us = 6 + 2 * p;
        const int Ts = (us >> 2) & 15, kks = (us >> 1) & 1, bs = Ts & 1;
        stageA(Ts, bs, kks);
        stageB(Ts, bs, kks);
        __builtin_amdgcn_sched_barrier(0);
        __builtin_amdgcn_s_setprio(1);
#pragma unroll
        for (int j = 0; j < 4; ++j)
#pragma unroll
            for (int i = 0; i < 8; ++i)
                acc[i][j] = __builtin_amdgcn_mfma_f32_16x16x32_bf16(fu[i], fu[8 + j], acc[i][j], 0, 0, 0);
        __builtin_amdgcn_s_setprio(0);
        __builtin_amdgcn_sched_barrier(0);
        asm volatile("s_waitcnt vmcnt(4)" ::: "memory");
        __builtin_amdgcn_s_barrier();
        __builtin_amdgcn_sched_barrier(0);
    };

    for (int p = 0; p < 32; p += 2) {
        phase(p,     F0, F1);
        phase(p + 1, F1, F0);
    }

    asm volatile("s_waitcnt vmcnt(0)" ::: "memory");

    const int r0 = (lane >> 4) * 4;
    const int cl = lane & 15;
#pragma unroll
    for (int i = 0; i < 8; ++i)
#pragma unroll
        for (int j = 0; j < 4; ++j) {
            const long m = bm + wm * 128 + i * 16 + r0;
            const int n = bn + wn * 64 + j * 16 + cl;
#pragma unroll
            for (int rr = 0; rr < 4; ++rr)
                C[(m + rr) * (long)VV + n] = acc[i][j][rr];
        }
}

extern "C" void kernel_launch(void* const* d_in, const int* in_sizes, int n_in,
                              void* d_out, int out_size, void* d_ws, size_t ws_size,
                              hipStream_t stream)
{
    (void)in_sizes; (void)n_in; (void)out_size;
    const int*   ids   = (const int*)d_in[0];
    const float* emb   = (const float*)d_in[1];
    const float* pos   = (const float*)d_in[2];
    const float* tors  = (const float*)d_in[3];
    const float* ln1g  = (const float*)d_in[4];
    const float* ln1b  = (const float*)d_in[5];
    const float* baseW = (const float*)d_in[6];
    const float* W1    = (const float*)d_in[7];
    const float* W2    = (const float*)d_in[8];
    const float* gate  = (const float*)d_in[9];
    const float* propW = (const float*)d_in[10];
    const float* propb = (const float*)d_in[11];
    const float* ln2g  = (const float*)d_in[12];
    const float* ln2b  = (const float*)d_in[13];
    const float* outg  = (const float*)d_in[14];
    const float* outb  = (const float*)d_in[15];
    const float* lmW   = (const float*)d_in[16];

    char* ws = (char*)d_ws;

    if (ws_size >= (144ul << 20)) {
        // hoisted layout: all weight prep up front, off the layer critical path
        float* h      = (float*)(ws);                    // 0..8 MB
        u16*   hn     = (u16*)  (ws + (8l  << 20));      // 8..12 MB
        u16*   Wcat0  = (u16*)  (ws + (12l << 20));      // 12..18 MB
        u16*   Wcat1  = (u16*)  (ws + (18l << 20));      // 18..24 MB
        u16*   W2eff0 = (u16*)  (ws + (24l << 20));      // 24..28 MB
        u16*   W2eff1 = (u16*)  (ws + (28l << 20));      // 28..32 MB
        float* C      = (float*)(ws + (32l << 20));      // 32..40 MB
        u16*   t      = (u16*)  (ws + (40l << 20));      // 40..48 MB
        float* Cpart  = (float*)(ws + (48l << 20));      // 48..80 MB [4][2048][1024] f32
        u16*   lmWbf  = (u16*)  (ws + (80l << 20));      // 80..142.5 MB

        mega_prep_kernel<<<8192, 256, 0, stream>>>(
            baseW, W1, W2, gate, tors, propW, propb, lmW,
            Wcat0, W2eff0, Wcat1, W2eff1, lmWbf);
        embed_ln_kernel<<<MM, 256, 0, stream>>>(ids, emb, pos, ln1g, ln1b, h, hn);

        for (int l = 0; l < 2; l++) {
            gemm_t<3><<<dim3(16, 24), 256, 0, stream>>>(
                hn, l ? Wcat1 : Wcat0, C, t, 1024, 1024, 0);
            gemm_t<5><<<dim3(16, 8, 4), 256, 0, stream>>>(
                t, l ? W2eff1 : W2eff0, Cpart, nullptr, 512, 2048, 1024);
            resln2_kernel<<<MM, 256, 0, stream>>>(
                h, C, Cpart, ln2g + (long)l * D, ln2b + (long)l * D,
                l == 0 ? ln1g + D : outg, l == 0 ? ln1b + D : outb, hn);
        }

        gemm256_kernel<<<dim3(8, 125), 512, 0, stream>>>(hn, lmWbf, (float*)d_out);
    } else {
        // fallback: proven r18 layout/sequence (386.7 us)
        float* h     = (float*)(ws);                    // 0..8 MB
        u16*   hn    = (u16*)  (ws + (8l  << 20));      // 8..12 MB
        u16*   Wcat  = (u16*)  (ws + (12l << 20));      // 12..18 MB
        float* C     = (float*)(ws + (18l << 20));      // 18..26 MB
        u16*   t     = (u16*)  (ws + (26l << 20));      // 26..34 MB
        u16*   W2eff = (u16*)  (ws + (34l << 20));      // 34..38 MB
        float* Cpart = (float*)(ws + (38l << 20));      // 38..70 MB
        u16*   lmWbf = (u16*)  (ws + (12l << 20));      // overlay after layers

        embed_ln_kernel<<<MM, 256, 0, stream>>>(ids, emb, pos, ln1g, ln1b, h, hn);

        for (int l = 0; l < 2; l++) {
            prep_kernel<<<3072, 256, 0, stream>>>(
                baseW + (long)l * D * D, W1 + (long)l * 4 * HH * D,
                W2 + (long)l * 4 * D * HH, gate + (long)l * 4 * D, tors,
                propW + l * 16, propb + l * 4, Wcat, W2eff);
            gemm_t<3><<<dim3(16, 24), 256, 0, stream>>>(hn, Wcat, C, t, 1024, 1024, 0);
            gemm_t<5><<<dim3(16, 8, 4), 256, 0, stream>>>(t, W2eff, Cpart, nullptr, 512, 2048, 1024);
            resln2_kernel<<<MM, 256, 0, stream>>>(
                h, C, Cpart, ln2g + (long)l * D, ln2b + (long)l * D,
                l == 0 ? ln1g + D : outg, l == 0 ? ln1b + D : outb, hn);
        }

        cvt_kernel<<<2048, 256, 0, stream>>>(lmW, lmWbf, VV * D / 4);
        gemm256_kernel<<<dim3(8, 125), 512, 0, stream>>>(hn, lmWbf, (float*)d_out);
    }
}

// Round 20
// 386.355 us; speedup vs baseline: 1.0151x; 1.0151x over previous
//
#include <hip/hip_runtime.h>
#include <math.h>

typedef unsigned short u16;
typedef short s16x8 __attribute__((ext_vector_type(8)));
typedef float f32x4 __attribute__((ext_vector_type(4)));
typedef u16 u16x4 __attribute__((ext_vector_type(4)));

#define D 1024
#define MM 2048   // B*S
#define HH 512
#define VV 32000

static __device__ __forceinline__ u16 f2bf(float f) {
    union { float f; unsigned int i; } c; c.f = f;
    unsigned int x = c.i;
    return (u16)((x + 0x7fffu + ((x >> 16) & 1u)) >> 16);  // RNE
}
static __device__ __forceinline__ float sigm(float x) { return 1.0f / (1.0f + expf(-x)); }

static __device__ __forceinline__ void load_lds16(const u16* g, u16* l) {
    __builtin_amdgcn_global_load_lds(
        (const __attribute__((address_space(1))) unsigned int*)g,
        (__attribute__((address_space(3))) unsigned int*)l, 16, 0, 0);
}

// ---------------- f32 -> bf16 convert, NT input ----------------
__global__ __launch_bounds__(256) void cvt_kernel(const float* __restrict__ in,
                                                  u16* __restrict__ out, const int n4)
{
    for (int i = blockIdx.x * 256 + threadIdx.x; i < n4; i += gridDim.x * 256) {
        f32x4 v = __builtin_nontemporal_load((const f32x4*)in + i);
        u16x4 o;
#pragma unroll
        for (int j = 0; j < 4; j++) o[j] = f2bf(v[j]);
        ((u16x4*)out)[i] = o;
    }
}

// ---------------- embed + LN1[0] ----------------
__global__ __launch_bounds__(256) void embed_ln_kernel(const int* __restrict__ ids,
    const float* __restrict__ emb, const float* __restrict__ pos,
    const float* __restrict__ g, const float* __restrict__ b,
    float* __restrict__ h, u16* __restrict__ hn)
{
    const int m = blockIdx.x;
    const int s = m & 1023;
    const long id = ids[m];
    const int d = threadIdx.x * 4;
    f32x4 ev = *(const f32x4*)&emb[id * D + d];
    f32x4 pv = *(const f32x4*)&pos[(long)s * D + d];
    f32x4 x;
#pragma unroll
    for (int i = 0; i < 4; i++) x[i] = ev[i] + pv[i];
    *(f32x4*)&h[(long)m * D + d] = x;

    float sm = x[0] + x[1] + x[2] + x[3];
    float ss = x[0]*x[0] + x[1]*x[1] + x[2]*x[2] + x[3]*x[3];
#pragma unroll
    for (int off = 32; off; off >>= 1) { sm += __shfl_xor(sm, off); ss += __shfl_xor(ss, off); }
    __shared__ float red[8];
    const int wid = threadIdx.x >> 6;
    if ((threadIdx.x & 63) == 0) { red[wid] = sm; red[4 + wid] = ss; }
    __syncthreads();
    sm = red[0] + red[1] + red[2] + red[3];
    ss = red[4] + red[5] + red[6] + red[7];
    const float mu = sm * (1.0f / D);
    const float rstd = rsqrtf(ss * (1.0f / D) - mu * mu + 1e-5f);
    f32x4 gv = *(const f32x4*)&g[d];
    f32x4 bv = *(const f32x4*)&b[d];
    u16x4 o;
#pragma unroll
    for (int i = 0; i < 4; i++) o[i] = f2bf((x[i] - mu) * rstd * gv[i] + bv[i]);
    *(u16x4*)&hn[(long)m * D + d] = o;
}

// ------- fused: h = LN2(h + 0.3*(C + P0+P1+P2+P3)); hn = bf16(LNnext(h)) -------
__global__ __launch_bounds__(256) void resln2_kernel(float* __restrict__ h,
    const float* __restrict__ c, const float* __restrict__ P,
    const float* __restrict__ g2, const float* __restrict__ b2,
    const float* __restrict__ gn, const float* __restrict__ bn_, u16* __restrict__ hn)
{
    const int row = blockIdx.x;
    const int d = threadIdx.x * 4;
    const long off = (long)row * D + d;
    f32x4 x = *(const f32x4*)&h[off];
    f32x4 cv = *(const f32x4*)&c[off];
    f32x4 p0 = *(const f32x4*)&P[off];
    f32x4 p1 = *(const f32x4*)&P[off + (1l << 21)];
    f32x4 p2 = *(const f32x4*)&P[off + (2l << 21)];
    f32x4 p3 = *(const f32x4*)&P[off + (3l << 21)];
#pragma unroll
    for (int i = 0; i < 4; i++) x[i] += 0.3f * (cv[i] + ((p0[i] + p1[i]) + (p2[i] + p3[i])));
    float sm = x[0] + x[1] + x[2] + x[3];
    float ss = x[0]*x[0] + x[1]*x[1] + x[2]*x[2] + x[3]*x[3];
#pragma unroll
    for (int off2 = 32; off2; off2 >>= 1) { sm += __shfl_xor(sm, off2); ss += __shfl_xor(ss, off2); }
    __shared__ float red[8];
    const int wid = threadIdx.x >> 6;
    if ((threadIdx.x & 63) == 0) { red[wid] = sm; red[4 + wid] = ss; }
    __syncthreads();
    sm = red[0] + red[1] + red[2] + red[3];
    ss = red[4] + red[5] + red[6] + red[7];
    float mu = sm * (1.0f / D);
    float rstd = rsqrtf(ss * (1.0f / D) - mu * mu + 1e-5f);
    f32x4 g2v = *(const f32x4*)&g2[d];
    f32x4 b2v = *(const f32x4*)&b2[d];
    f32x4 y;
#pragma unroll
    for (int i = 0; i < 4; i++) y[i] = (x[i] - mu) * rstd * g2v[i] + b2v[i];
    *(f32x4*)&h[off] = y;

    sm = y[0] + y[1] + y[2] + y[3];
    ss = y[0]*y[0] + y[1]*y[1] + y[2]*y[2] + y[3]*y[3];
#pragma unroll
    for (int off2 = 32; off2; off2 >>= 1) { sm += __shfl_xor(sm, off2); ss += __shfl_xor(ss, off2); }
    __syncthreads();
    if ((threadIdx.x & 63) == 0) { red[wid] = sm; red[4 + wid] = ss; }
    __syncthreads();
    sm = red[0] + red[1] + red[2] + red[3];
    ss = red[4] + red[5] + red[6] + red[7];
    mu = sm * (1.0f / D);
    rstd = rsqrtf(ss * (1.0f / D) - mu * mu + 1e-5f);
    f32x4 gnv = *(const f32x4*)&gn[d];
    f32x4 bnv = *(const f32x4*)&bn_[d];
    u16x4 o;
#pragma unroll
    for (int i = 0; i < 4; i++) o[i] = f2bf((y[i] - mu) * rstd * gnv[i] + bnv[i]);
    *(u16x4*)&hn[off] = o;
}

// ---------------- prep: Wcat (cvtcat) + W2eff (scale+exc) in ONE launch ----------------
__global__ __launch_bounds__(256) void prep_kernel(
    const float* __restrict__ baseW, const float* __restrict__ W1,
    const float* __restrict__ W2l, const float* __restrict__ gatel,
    const float* __restrict__ tors, const float* __restrict__ pW,
    const float* __restrict__ pb, u16* __restrict__ Wcat, u16* __restrict__ W2eff)
{
    int bid = blockIdx.x;   // 3072 blocks
    if (bid < 1024) {
        const int B4 = 1024 * 1024 / 4;
#pragma unroll
        for (int it = 0; it < 3; ++it) {
            const int i = (it * 1024 + bid) * 256 + threadIdx.x;
            f32x4 v = (i < B4) ? __builtin_nontemporal_load((const f32x4*)baseW + i)
                               : __builtin_nontemporal_load((const f32x4*)W1 + (i - B4));
            u16x4 o;
#pragma unroll
            for (int j = 0; j < 4; j++) o[j] = f2bf(v[j]);
            ((u16x4*)Wcat)[i] = o;
        }
    } else {
        bid -= 1024;        // 2048 blocks for W2eff
        const float NS = 1.0f / (1.0f + expf(-0.70710678118654752f));
        float e[4], sum = 0.0f;
#pragma unroll
        for (int k = 0; k < 4; k++) {
            float a = pb[k] + 0.5f * (pW[k*4] + pW[k*4+1] + pW[k*4+2] + pW[k*4+3]);
            e[k] = 0.6f * sigm(a) + 0.4f * NS;
            sum += e[k];
        }
        const int n = bid >> 1;
        const int half = bid & 1;
        const int kh = half * 1024 + threadIdx.x * 4;
        const int k = kh >> 9;
        const int hh = kh & 511;
        const float f = sigm(gatel[k * D + n] + tors[n]) * (e[k] / sum);
        f32x4 w = __builtin_nontemporal_load((const f32x4*)&W2l[((long)k * D + n) * HH + hh]);
        u16x4 o;
#pragma unroll
        for (int i = 0; i < 4; i++) o[i] = f2bf(w[i] * f);
        *(u16x4*)&W2eff[(long)n * 2048 + kh] = o;
    }
}

// ---------------- layer GEMM: 128x128, 4 waves, BK=32, fragment-linear LDS ----------------
// EPI 3: mixed -> n<1024: f32 C; n>=1024: gelu->bf16 t. EPI 5: f32 store to partial[z].
template<int EPI>
__global__ __launch_bounds__(256) void gemm_t(
    const u16* __restrict__ A, const u16* __restrict__ W,
    float* __restrict__ Cf, u16* __restrict__ Cb,
    const int Kloop, const int ldk, const long ldc)
{
    if (EPI == 5) { A += blockIdx.z * 512; W += blockIdx.z * 512; Cf += (long)blockIdx.z << 21; }

    const int gx = gridDim.x;
    const int nwg = gx * gridDim.y;
    int lin = blockIdx.y * gx + blockIdx.x;
    lin = (lin & 7) * (nwg >> 3) + (lin >> 3);
    const int bm = (lin % gx) * 128;
    const int bn = (lin / gx) * 128;

    __shared__ __align__(16) u16 AB[8192];

    const int tid = threadIdx.x, lane = tid & 63, w = tid >> 6;
    const int wm = w >> 1, wn = w & 1;
    const int l15 = lane & 15, lk8 = (lane >> 4) * 8;

    const u16* src[4];
    u16* dst[4];
#pragma unroll
    for (int ci = 0; ci < 4; ++ci) {
        const int c = w + ci * 4;
        src[ci] = (c < 8 ? A + (long)(bm + c * 16 + l15) * ldk
                         : W + (long)(bn + (c - 8) * 16 + l15) * ldk) + lk8;
        dst[ci] = AB + c * 512;
    }

    f32x4 acc[4][4];
#pragma unroll
    for (int i = 0; i < 4; ++i)
#pragma unroll
        for (int j = 0; j < 4; ++j) acc[i][j] = f32x4{0.f, 0.f, 0.f, 0.f};

    for (int k0 = 0; k0 < Kloop; k0 += 32) {
        __syncthreads();
#pragma unroll
        for (int ci = 0; ci < 4; ++ci) load_lds16(src[ci] + k0, dst[ci]);
        __syncthreads();
        s16x8 a[4], b[4];
#pragma unroll
        for (int i = 0; i < 4; ++i) a[i] = *(const s16x8*)(AB + (wm * 4 + i) * 512 + lane * 8);
#pragma unroll
        for (int j = 0; j < 4; ++j) b[j] = *(const s16x8*)(AB + (8 + wn * 4 + j) * 512 + lane * 8);
#pragma unroll
        for (int i = 0; i < 4; ++i)
#pragma unroll
            for (int j = 0; j < 4; ++j)
                acc[i][j] = __builtin_amdgcn_mfma_f32_16x16x32_bf16(a[i], b[j], acc[i][j], 0, 0, 0);
    }

    const int r0 = (lane >> 4) * 4;
#pragma unroll
    for (int i = 0; i < 4; ++i) {
#pragma unroll
        for (int j = 0; j < 4; ++j) {
            const int n = bn + wn * 64 + j * 16 + l15;
#pragma unroll
            for (int rr = 0; rr < 4; ++rr) {
                const int m = bm + wm * 64 + i * 16 + r0 + rr;
                const float v = acc[i][j][rr];
                if (EPI == 3) {
                    if (n < 1024) {
                        Cf[(long)m * 1024 + n] = v;
                    } else {
                        const float gel = 0.5f * v * (1.0f + erff(v * 0.70710678118654752f));
                        Cb[(long)m * 2048 + (n - 1024)] = f2bf(gel);
                    }
                } else {  // EPI == 5: plain f32 partial store
                    Cf[(long)m * ldc + n] = v;
                }
            }
        }
    }
}

// ================= lm_head: 256x256, BK=64, frag-prefetch (r8 engine, plain stores) ========
#define AU16  16384
#define HALFU 8192
#define BB0   32768

__global__ __launch_bounds__(512, 2) void gemm256_kernel(
    const u16* __restrict__ Ag, const u16* __restrict__ Wg, float* __restrict__ C)
{
    __shared__ __align__(16) u16 lds[65536];

    const int nwg = gridDim.x * gridDim.y;
    int lin = blockIdx.y * gridDim.x + blockIdx.x;
    lin = (lin & 7) * (nwg >> 3) + (lin >> 3);
    const int bm = (lin & 7) * 256;
    const int bn = (lin >> 3) * 256;

    const int tid = threadIdx.x;
    const int lane = tid & 63;
    const int w = tid >> 6;
    const int wm = w >> 2;
    const int wn = w & 3;

    const u16* aSrc = Ag + (long)(bm + w * 16 + (lane & 15)) * 1024 + ((lane >> 4) * 8);
    const u16* bSrc = Wg + (long)(bn + w * 16 + (lane & 15)) * 1024 + ((lane >> 4) * 8);
    u16* aDst = lds + w * 1024;
    u16* bDst = lds + BB0 + w * 1024;

    auto stageA = [&](int kt, int b, int kk) {
        const long co = (long)kt * 64 + kk * 32;
        load_lds16(aSrc + co,               aDst + b * AU16 + kk * 512);
        load_lds16(aSrc + co + 128 * 1024L, aDst + b * AU16 + HALFU + kk * 512);
    };
    auto stageB = [&](int kt, int b, int kk) {
        const long co = (long)kt * 64 + kk * 32;
        load_lds16(bSrc + co,               bDst + b * AU16 + kk * 512);
        load_lds16(bSrc + co + 128 * 1024L, bDst + b * AU16 + HALFU + kk * 512);
    };

    const u16* aRd = lds + wm * HALFU + lane * 8;
    const u16* bRd = lds + BB0 + (wn >> 1) * HALFU + (wn & 1) * 4096 + lane * 8;

    f32x4 acc[8][4];
#pragma unroll
    for (int i = 0; i < 8; ++i)
#pragma unroll
        for (int j = 0; j < 4; ++j) acc[i][j] = f32x4{0.f, 0.f, 0.f, 0.f};

    s16x8 F0[12], F1[12];

    stageA(0, 0, 0); stageB(0, 0, 0);
    stageA(0, 0, 1); stageB(0, 0, 1);
    stageA(1, 1, 0); stageB(1, 1, 0);
    asm volatile("s_waitcnt vmcnt(4)" ::: "memory");
    __builtin_amdgcn_s_barrier();
    __builtin_amdgcn_sched_barrier(0);

#pragma unroll
    for (int i = 0; i < 8; ++i) F0[i] = *(const s16x8*)(aRd + i * 1024);
#pragma unroll
    for (int j = 0; j < 4; ++j) F0[8 + j] = *(const s16x8*)(bRd + j * 1024);

    auto phase = [&](int p, s16x8 (&fu)[12], s16x8 (&fl)[12]) {
        const int pr = p + 1;
        const int Tr = (pr >> 1) & 15, kkr = pr & 1, br = Tr & 1;
        const u16* aR = aRd + br * AU16 + kkr * 512;
        const u16* bR = bRd + br * AU16 + kkr * 512;
#pragma unroll
        for (int i = 0; i < 8; ++i) fl[i] = *(const s16x8*)(aR + i * 1024);
#pragma unroll
        for (int j = 0; j < 4; ++j) fl[8 + j] = *(const s16x8*)(bR + j * 1024);
        const int us = 6 + 2 * p;
        const int Ts = (us >> 2) & 15, kks = (us >> 1) & 1, bs = Ts & 1;
        stageA(Ts, bs, kks);
        stageB(Ts, bs, kks);
        __builtin_amdgcn_sched_barrier(0);
        __builtin_amdgcn_s_setprio(1);
#pragma unroll
        for (int j = 0; j < 4; ++j)
#pragma unroll
            for (int i = 0; i < 8; ++i)
                acc[i][j] = __builtin_amdgcn_mfma_f32_16x16x32_bf16(fu[i], fu[8 + j], acc[i][j], 0, 0, 0);
        __builtin_amdgcn_s_setprio(0);
        __builtin_amdgcn_sched_barrier(0);
        asm volatile("s_waitcnt vmcnt(4)" ::: "memory");
        __builtin_amdgcn_s_barrier();
        __builtin_amdgcn_sched_barrier(0);
    };

    for (int p = 0; p < 32; p += 2) {
        phase(p,     F0, F1);
        phase(p + 1, F1, F0);
    }

    asm volatile("s_waitcnt vmcnt(0)" ::: "memory");

    const int r0 = (lane >> 4) * 4;
    const int cl = lane & 15;
#pragma unroll
    for (int i = 0; i < 8; ++i)
#pragma unroll
        for (int j = 0; j < 4; ++j) {
            const long m = bm + wm * 128 + i * 16 + r0;
            const int n = bn + wn * 64 + j * 16 + cl;
#pragma unroll
            for (int rr = 0; rr < 4; ++rr)
                C[(m + rr) * (long)VV + n] = acc[i][j][rr];
        }
}

extern "C" void kernel_launch(void* const* d_in, const int* in_sizes, int n_in,
                              void* d_out, int out_size, void* d_ws, size_t ws_size,
                              hipStream_t stream)
{
    (void)in_sizes; (void)n_in; (void)out_size; (void)ws_size;
    const int*   ids   = (const int*)d_in[0];
    const float* emb   = (const float*)d_in[1];
    const float* pos   = (const float*)d_in[2];
    const float* tors  = (const float*)d_in[3];
    const float* ln1g  = (const float*)d_in[4];
    const float* ln1b  = (const float*)d_in[5];
    const float* baseW = (const float*)d_in[6];
    const float* W1    = (const float*)d_in[7];
    const float* W2    = (const float*)d_in[8];
    const float* gate  = (const float*)d_in[9];
    const float* propW = (const float*)d_in[10];
    const float* propb = (const float*)d_in[11];
    const float* ln2g  = (const float*)d_in[12];
    const float* ln2b  = (const float*)d_in[13];
    const float* outg  = (const float*)d_in[14];
    const float* outb  = (const float*)d_in[15];
    const float* lmW   = (const float*)d_in[16];

    char* ws = (char*)d_ws;
    float* h     = (float*)(ws);                    // 0..8 MB
    u16*   hn    = (u16*)  (ws + (8l  << 20));      // 8..12 MB
    u16*   Wcat  = (u16*)  (ws + (12l << 20));      // 12..18 MB
    float* C     = (float*)(ws + (18l << 20));      // 18..26 MB
    u16*   t     = (u16*)  (ws + (26l << 20));      // 26..34 MB
    u16*   W2eff = (u16*)  (ws + (34l << 20));      // 34..38 MB
    float* Cpart = (float*)(ws + (38l << 20));      // 38..70 MB [4][2048][1024] f32
    u16*   lmWbf = (u16*)  (ws + (12l << 20));      // overlay: 12..74.5 MB (after layers)

    embed_ln_kernel<<<MM, 256, 0, stream>>>(ids, emb, pos, ln1g, ln1b, h, hn);

    for (int l = 0; l < 2; l++) {
        prep_kernel<<<3072, 256, 0, stream>>>(
            baseW + (long)l * D * D, W1 + (long)l * 4 * HH * D,
            W2 + (long)l * 4 * D * HH, gate + (long)l * 4 * D, tors,
            propW + l * 16, propb + l * 4, Wcat, W2eff);
        // {base -> C(f32), t = gelu(hn @ W1^T)} fused GEMM, N = 3072
        gemm_t<3><<<dim3(16, 24), 256, 0, stream>>>(hn, Wcat, C, t, 1024, 1024, 0);
        // Cpart[z] = t @ W2eff^T (K-quarter z), plain stores — no atomics
        gemm_t<5><<<dim3(16, 8, 4), 256, 0, stream>>>(t, W2eff, Cpart, nullptr, 512, 2048, 1024);
        // h = LN2(h + 0.3*(C + sum Cpart)); hn = bf16(LNnext(h))
        resln2_kernel<<<MM, 256, 0, stream>>>(
            h, C, Cpart, ln2g + (long)l * D, ln2b + (long)l * D,
            l == 0 ? ln1g + D : outg, l == 0 ? ln1b + D : outb, hn);
    }

    cvt_kernel<<<2048, 256, 0, stream>>>(lmW, lmWbf, VV * D / 4);
    // lm_head: r8 engine (measured-best), plain stores
    gemm256_kernel<<<dim3(8, 125), 512, 0, stream>>>(hn, lmWbf, (float*)d_out);
}